// Round 9
// baseline (90.390 us; speedup 1.0000x reference)
//
#include <hip/hip_runtime.h>
#include <math.h>

#define LAMB    5.0f
#define LOG_PI  1.144729885849400f
#define L2E     1.4426950408889634f
#define LN2     0.6931471805599453f
#define LAM2E   7.213475204444817f   // LAMB * L2E

constexpr int HID = 100;
constexpr int KC  = 30;

typedef float    v2f __attribute__((ext_vector_type(2)));
typedef _Float16 h2  __attribute__((ext_vector_type(2)));

__device__ __forceinline__ v2f splat2(float s) { return (v2f){s, s}; }
__device__ __forceinline__ v2f fma2(v2f a, v2f b, v2f c) { return __builtin_elementwise_fma(a, b, c); }
__device__ __forceinline__ v2f max2(v2f a, v2f b) { return __builtin_elementwise_max(a, b); }

__device__ __forceinline__ float rcp_s(float x)  { return __builtin_amdgcn_rcpf(x); }
__device__ __forceinline__ float lg2_s(float x)  { return __builtin_amdgcn_logf(x); }   // log2
__device__ __forceinline__ float ex2_s(float x)  { return __builtin_amdgcn_exp2f(x); }  // 2^x
__device__ __forceinline__ v2f rcp2(v2f x)  { return (v2f){rcp_s(x.x), rcp_s(x.y)}; }
__device__ __forceinline__ v2f sqrt2(v2f x) { return (v2f){__builtin_amdgcn_sqrtf(x.x), __builtin_amdgcn_sqrtf(x.y)}; }
__device__ __forceinline__ v2f exp2v(v2f x) { return (v2f){ex2_s(x.x), ex2_s(x.y)}; }

// natural log1p (arg in (0,1] for softplus path), guarded for tiny u
__device__ __forceinline__ float log1p_s(float u) {
    float big = lg2_s(1.0f + u) * LN2;
    float sml = u * (1.0f - 0.5f * u);
    return (u > 1e-5f) ? big : sml;
}

// log2(1+u) elementwise, guarded for tiny u
__device__ __forceinline__ v2f log2_1p2(v2f u) {
    float bx = lg2_s(1.0f + u.x), by = lg2_s(1.0f + u.y);
    float sx = u.x * L2E * (1.0f - 0.5f * u.x);
    float sy = u.y * L2E * (1.0f - 0.5f * u.y);
    return (v2f){ (u.x > 1e-5f) ? bx : sx, (u.y > 1e-5f) ? by : sy };
}

// softplus = max(v,0) + log1p(exp(-|v|)), elementwise on v2f
__device__ __forceinline__ v2f softplus2(v2f v) {
    v2f e = exp2v((v2f){-fabsf(v.x) * L2E, -fabsf(v.y) * L2E});
    return max2(v, splat2(0.f)) + (v2f){log1p_s(e.x), log1p_s(e.y)};
}

// ---- merged prep: rbf table + f16 decoder weight pack + counter zero ----
// rbfc layout per pair kk (16 floats): cx(2), cy(2), q(2), w0(2), w1(2), pad(6)
// hb layout (units of h2): [0..49]=w1 row0, [50..99]=w1 row1, [100..149]=b1,
//   [150..199]=w2 col0, [200..249]=w2 col1; m-MLP at hb, f-MLP at hb+256.
__global__ __launch_bounds__(256) void prep(
    const float* __restrict__ Cc,   const float* __restrict__ Wc,
    const float* __restrict__ dmw1, const float* __restrict__ dmb1,
    const float* __restrict__ dmw2,
    const float* __restrict__ dfw1, const float* __restrict__ dfb1,
    const float* __restrict__ dfw2,
    float* __restrict__ rbfc, h2* __restrict__ hb,
    unsigned int* __restrict__ done_ctr)
{
    int t = threadIdx.x;
    if (t == 255) *done_ctr = 0u;
    if (t < KC / 2) {
        int k = 2 * t;
        float c00 = Cc[2 * k],     c01 = Cc[2 * k + 1];
        float c10 = Cc[2 * k + 2], c11 = Cc[2 * k + 3];
        float* p = &rbfc[16 * t];
        p[0] = 2.0f * LAM2E * c00;  p[1] = 2.0f * LAM2E * c10;
        p[2] = 2.0f * LAM2E * c01;  p[3] = 2.0f * LAM2E * c11;
        p[4] = -LAM2E * (c00 * c00 + c01 * c01);
        p[5] = -LAM2E * (c10 * c10 + c11 * c11);
        p[6] = fmaxf(Wc[2 * k],     0.f);  p[7] = fmaxf(Wc[2 * k + 2], 0.f);
        p[8] = fmaxf(Wc[2 * k + 1], 0.f);  p[9] = fmaxf(Wc[2 * k + 3], 0.f);
        p[10] = 0.f; p[11] = 0.f; p[12] = 0.f; p[13] = 0.f; p[14] = 0.f; p[15] = 0.f;
    }
    if (t >= 64 && t < 64 + HID / 2) {
        int tt = t - 64;
        int j = 2 * tt;
        h2* p = hb;
        p[tt]       = (h2){(_Float16)dmw1[j],        (_Float16)dmw1[j + 1]};
        p[50 + tt]  = (h2){(_Float16)dmw1[HID + j],  (_Float16)dmw1[HID + j + 1]};
        p[100 + tt] = (h2){(_Float16)dmb1[j],        (_Float16)dmb1[j + 1]};
        p[150 + tt] = (h2){(_Float16)dmw2[2 * j],    (_Float16)dmw2[2 * j + 2]};
        p[200 + tt] = (h2){(_Float16)dmw2[2 * j + 1],(_Float16)dmw2[2 * j + 3]};
    }
    if (t >= 128 && t < 128 + HID / 2) {
        int tt = t - 128;
        int j = 2 * tt;
        h2* p = hb + 256;
        p[tt]       = (h2){(_Float16)dfw1[j],        (_Float16)dfw1[j + 1]};
        p[50 + tt]  = (h2){(_Float16)dfw1[HID + j],  (_Float16)dfw1[HID + j + 1]};
        p[100 + tt] = (h2){(_Float16)dfb1[j],        (_Float16)dfb1[j + 1]};
        p[150 + tt] = (h2){(_Float16)dfw2[2 * j],    (_Float16)dfw2[2 * j + 2]};
        p[200 + tt] = (h2){(_Float16)dfw2[2 * j + 1],(_Float16)dfw2[2 * j + 3]};
    }
}

__global__ __launch_bounds__(256) void vae_main(
    const float* __restrict__ x,    const float* __restrict__ eps,
    const float* __restrict__ emw1, const float* __restrict__ emb1,
    const float* __restrict__ emw2, const float* __restrict__ emb2,
    const float* __restrict__ esw1, const float* __restrict__ esb1,
    const float* __restrict__ esw2, const float* __restrict__ esb2,
    const float* __restrict__ dmb2, const float* __restrict__ dfb2,
    const h2*    __restrict__ hb,
    const float* __restrict__ rbfc,
    float* __restrict__ out_elbo,  float* __restrict__ out_xmu,
    float* __restrict__ out_scale, float* __restrict__ out_z,
    float* __restrict__ out_zmu,   float* __restrict__ out_zstd,
    float* __restrict__ partial,   unsigned int* __restrict__ done_ctr,
    int n)
{
    const int i = blockIdx.x * 256 + threadIdx.x;

    float val = 0.0f;

    if (i < n) {
        const v2f xv = *(const v2f*)&x[2 * i];
        const v2f ev = *(const v2f*)&eps[2 * i];
        const v2f vx0 = splat2(xv.x), vx1 = splat2(xv.y);

        // ---- encoder MLPs (mu, std): f32 (z must be exact) ----
        v2f accm = splat2(0.f), accs = splat2(0.f);
#pragma unroll 10
        for (int j = 0; j < HID; j += 2) {
            v2f w1a = *(const v2f*)&emw1[j];
            v2f w1b = *(const v2f*)&emw1[HID + j];
            v2f b1  = *(const v2f*)&emb1[j];
            v2f h   = max2(fma2(vx0, w1a, fma2(vx1, w1b, b1)), splat2(0.f));
            v2f w2a = *(const v2f*)&emw2[2 * j];
            v2f w2b = *(const v2f*)&emw2[2 * j + 2];
            accm = fma2(splat2(h.x), w2a, accm);
            accm = fma2(splat2(h.y), w2b, accm);

            v2f s1a = *(const v2f*)&esw1[j];
            v2f s1b = *(const v2f*)&esw1[HID + j];
            v2f sb1 = *(const v2f*)&esb1[j];
            v2f hs  = max2(fma2(vx0, s1a, fma2(vx1, s1b, sb1)), splat2(0.f));
            v2f d0 = *(const v2f*)&esw2[2 * j];
            v2f d1 = *(const v2f*)&esw2[2 * j + 2];
            accs = fma2(splat2(hs.x), d0, accs);
            accs = fma2(splat2(hs.y), d1, accs);
        }
        const v2f zmu  = accm + *(const v2f*)&emb2[0];
        const v2f zstd = softplus2(accs + *(const v2f*)&esb2[0]);
        const v2f sig  = sqrt2(zstd);
        const v2f z    = fma2(sig, ev, zmu);

        // ---- decoder MLPs (mu, df): packed f16 layer1 + fdot2(f32-acc) layer2 ----
        const _Float16 z0f = (_Float16)z.x;
        const _Float16 z1f = (_Float16)z.y;
        const h2 z0h = (h2){z0f, z0f};
        const h2 z1h = (h2){z1f, z1f};
        const h2 hzero = {(_Float16)0.f, (_Float16)0.f};
        float dm0 = 0.f, dm1 = 0.f, dg0 = 0.f, dg1 = 0.f;
        const h2* hm = hb;
        const h2* hf = hb + 256;
#pragma unroll 10
        for (int jj = 0; jj < HID / 2; ++jj) {
            h2 pm = __builtin_elementwise_fma(z0h, hm[jj], hm[100 + jj]);
            pm = __builtin_elementwise_fma(z1h, hm[50 + jj], pm);
            pm = __builtin_elementwise_max(pm, hzero);
            dm0 = __builtin_amdgcn_fdot2(pm, hm[150 + jj], dm0, false);
            dm1 = __builtin_amdgcn_fdot2(pm, hm[200 + jj], dm1, false);

            h2 pf = __builtin_elementwise_fma(z0h, hf[jj], hf[100 + jj]);
            pf = __builtin_elementwise_fma(z1h, hf[50 + jj], pf);
            pf = __builtin_elementwise_max(pf, hzero);
            dg0 = __builtin_amdgcn_fdot2(pf, hf[150 + jj], dg0, false);
            dg1 = __builtin_amdgcn_fdot2(pf, hf[200 + jj], dg1, false);
        }
        const v2f xmu = (v2f){dm0, dm1} + *(const v2f*)&dmb2[0];
        const v2f df  = softplus2((v2f){dg0, dg1} + *(const v2f*)&dfb2[0]);

        // ---- RBF inverse-scale, pair-packed over k (f32, z exact) ----
        const float zz = z.x * z.x + z.y * z.y;
        const v2f z0s = splat2(z.x), z1s = splat2(z.y);
        const v2f u0s = splat2(-LAM2E * zz);
        v2f acc0 = splat2(0.f), acc1 = splat2(0.f);
#pragma unroll
        for (int kk = 0; kk < KC / 2; ++kk) {
            const float* p = &rbfc[16 * kk];
            v2f cx = *(const v2f*)&p[0];
            v2f cy = *(const v2f*)&p[2];
            v2f qq = *(const v2f*)&p[4];
            v2f w0p = *(const v2f*)&p[6];
            v2f w1p = *(const v2f*)&p[8];
            v2f arg = fma2(cx, z0s, fma2(cy, z1s, qq + u0s));
            v2f e = exp2v(arg);
            acc0 = fma2(e, w0p, acc0);
            acc1 = fma2(e, w1p, acc1);
        }
        const v2f ia = (v2f){acc0.x + acc0.y, acc1.x + acc1.y} + splat2(1e-10f);
        const v2f vscale = rcp2(ia);

        // ---- student-t log-prob sum over dims, log-product fused ----
        // lp_d = g(a) - 0.5 ln df - 0.5 ln pi + ln ia - 0.5(df+1) ln(1+u)
        // g(a) = lgamma(a+1/2)-lgamma(a) = 0.5 ln b + ln r + p(t), b=a+3, t=1/(2b)
        const v2f a  = splat2(0.5f) * df;
        const v2f b  = a + splat2(3.0f);
        const v2f rb = rcp2(b);
        const v2f t  = splat2(0.5f) * rb;
        const v2f t2 = t * t;
        const v2f p  = t * (splat2(-0.25f) + t2 * (splat2(0.0416666667f) + t2 * splat2(-0.05f)));

        const v2f a1 = a + splat2(1.0f), a2 = a + splat2(2.0f);
        const v2f h1 = a + splat2(0.5f), h2v = a + splat2(1.5f), h3 = a + splat2(2.5f);
        const v2f pn = a * a1 * a2;
        const v2f pd = h1 * h2v * h3;
        const float rprod = (pn.x * pn.y) * rcp_s(pd.x * pd.y);

        const v2f rdf = rcp2(df);
        const float bb_dd = (b.x * b.y) * (rdf.x * rdf.y);
        const float S1 = lg2_s(bb_dd);                       // log2(b.x b.y / (df.x df.y))
        const float S2 = lg2_s(rprod * (ia.x * ia.y));       // log2(r-prod * ia-prod)

        const v2f y  = (xv - xmu) * ia;
        const v2f u  = y * y * rdf;
        const v2f L2 = log2_1p2(u);
        const v2f dfp1 = df + splat2(1.0f);

        const float Szstd = lg2_s(zstd.x * zstd.y);          // for KL

        const float A = 0.5f * S1 + S2
                      - 0.5f * (dfp1.x * L2.x + dfp1.y * L2.y)
                      + 0.5f * Szstd;
        const float ee = ev.x * ev.x + ev.y * ev.y;
        val = LN2 * A + (p.x + p.y) - LOG_PI + 0.5f * ee - 0.5f * zz;

        // ---- outputs ----
        *(v2f*)&out_xmu[2 * i]   = xmu;
        *(v2f*)&out_scale[2 * i] = vscale;
        *(v2f*)&out_z[2 * i]     = z;
        *(v2f*)&out_zmu[2 * i]   = zmu;
        *(v2f*)&out_zstd[2 * i]  = zstd;
    }

    // ---- deterministic block reduction of val ----
#pragma unroll
    for (int off = 32; off > 0; off >>= 1)
        val += __shfl_down(val, off, 64);

    __shared__ float wsum[4];
    const int lane = threadIdx.x & 63;
    const int wid  = threadIdx.x >> 6;
    if (lane == 0) wsum[wid] = val;
    __syncthreads();

    // ---- last-block-done final reduction (deterministic fixed-order sum) ----
    __shared__ bool is_last;
    if (threadIdx.x == 0) {
        partial[blockIdx.x] = (wsum[0] + wsum[1]) + (wsum[2] + wsum[3]);
        __threadfence();
        unsigned int old = atomicAdd(done_ctr, 1u);
        is_last = (old == (unsigned int)(gridDim.x - 1));
    }
    __syncthreads();

    if (is_last) {
        const int nblk = gridDim.x;
        double acc = 0.0;
        for (int j = threadIdx.x; j < nblk; j += 256) {
            float pj = __hip_atomic_load(&partial[j], __ATOMIC_RELAXED,
                                         __HIP_MEMORY_SCOPE_AGENT);
            acc += (double)pj;
        }
        __shared__ double sh[256];
        sh[threadIdx.x] = acc;
        __syncthreads();
#pragma unroll
        for (int s = 128; s > 0; s >>= 1) {
            if (threadIdx.x < s) sh[threadIdx.x] += sh[threadIdx.x + s];
            __syncthreads();
        }
        if (threadIdx.x == 0) out_elbo[0] = (float)(sh[0] / (double)n);
    }
}

extern "C" void kernel_launch(void* const* d_in, const int* in_sizes, int n_in,
                              void* d_out, int out_size, void* d_ws, size_t ws_size,
                              hipStream_t stream) {
    const float* x    = (const float*)d_in[0];
    const float* eps  = (const float*)d_in[1];
    const float* emw1 = (const float*)d_in[2];
    const float* emb1 = (const float*)d_in[3];
    const float* emw2 = (const float*)d_in[4];
    const float* emb2 = (const float*)d_in[5];
    const float* esw1 = (const float*)d_in[6];
    const float* esb1 = (const float*)d_in[7];
    const float* esw2 = (const float*)d_in[8];
    const float* esb2 = (const float*)d_in[9];
    const float* dmw1 = (const float*)d_in[10];
    const float* dmb1 = (const float*)d_in[11];
    const float* dmw2 = (const float*)d_in[12];
    const float* dmb2 = (const float*)d_in[13];
    const float* dfw1 = (const float*)d_in[14];
    const float* dfb1 = (const float*)d_in[15];
    const float* dfw2 = (const float*)d_in[16];
    const float* dfb2 = (const float*)d_in[17];
    const float* Cc   = (const float*)d_in[18];
    const float* Wc   = (const float*)d_in[19];

    const int n = in_sizes[0] / 2;      // N samples
    float* out = (float*)d_out;
    float* out_elbo  = out;
    float* out_xmu   = out + 1;
    float* out_scale = out + 1 + 2 * (size_t)n;
    float* out_z     = out + 1 + 4 * (size_t)n;
    float* out_zmu   = out + 1 + 6 * (size_t)n;
    float* out_zstd  = out + 1 + 8 * (size_t)n;

    float* partial      = (float*)d_ws;                       // [nblk] floats
    unsigned int* dctr  = (unsigned int*)((float*)d_ws + 3072);
    float* rbfc         = (float*)d_ws + 4096;                // [240] floats
    h2*    hb           = (h2*)((float*)d_ws + 8192);         // [512] half2

    const int nblk = (n + 255) / 256;

    prep<<<1, 256, 0, stream>>>(Cc, Wc, dmw1, dmb1, dmw2, dfw1, dfb1, dfw2,
                                rbfc, hb, dctr);

    vae_main<<<nblk, 256, 0, stream>>>(
        x, eps,
        emw1, emb1, emw2, emb2,
        esw1, esb1, esw2, esb2,
        dmb2, dfb2, hb, rbfc,
        out_elbo, out_xmu, out_scale, out_z, out_zmu, out_zstd,
        partial, dctr, n);
}

// Round 10
// 43.606 us; speedup vs baseline: 2.0729x; 2.0729x over previous
//
#include <hip/hip_runtime.h>
#include <math.h>

#define LAMB    5.0f
#define LOG_PI  1.144729885849400f
#define L2E     1.4426950408889634f
#define LN2     0.6931471805599453f
#define LAM2E   7.213475204444817f   // LAMB * L2E

constexpr int HID = 100;
constexpr int KC  = 30;

typedef float    v2f __attribute__((ext_vector_type(2)));
typedef _Float16 h2  __attribute__((ext_vector_type(2)));

__device__ __forceinline__ v2f splat2(float s) { return (v2f){s, s}; }
__device__ __forceinline__ v2f fma2(v2f a, v2f b, v2f c) { return __builtin_elementwise_fma(a, b, c); }
__device__ __forceinline__ v2f max2(v2f a, v2f b) { return __builtin_elementwise_max(a, b); }

__device__ __forceinline__ float rcp_s(float x)  { return __builtin_amdgcn_rcpf(x); }
__device__ __forceinline__ float lg2_s(float x)  { return __builtin_amdgcn_logf(x); }   // log2
__device__ __forceinline__ float ex2_s(float x)  { return __builtin_amdgcn_exp2f(x); }  // 2^x
__device__ __forceinline__ v2f rcp2(v2f x)  { return (v2f){rcp_s(x.x), rcp_s(x.y)}; }
__device__ __forceinline__ v2f sqrt2(v2f x) { return (v2f){__builtin_amdgcn_sqrtf(x.x), __builtin_amdgcn_sqrtf(x.y)}; }
__device__ __forceinline__ v2f exp2v(v2f x) { return (v2f){ex2_s(x.x), ex2_s(x.y)}; }

// natural log1p (arg in (0,1] for softplus path), guarded for tiny u
__device__ __forceinline__ float log1p_s(float u) {
    float big = lg2_s(1.0f + u) * LN2;
    float sml = u * (1.0f - 0.5f * u);
    return (u > 1e-5f) ? big : sml;
}

// log2(1+u) elementwise, guarded for tiny u
__device__ __forceinline__ v2f log2_1p2(v2f u) {
    float bx = lg2_s(1.0f + u.x), by = lg2_s(1.0f + u.y);
    float sx = u.x * L2E * (1.0f - 0.5f * u.x);
    float sy = u.y * L2E * (1.0f - 0.5f * u.y);
    return (v2f){ (u.x > 1e-5f) ? bx : sx, (u.y > 1e-5f) ? by : sy };
}

// softplus = max(v,0) + log1p(exp(-|v|)), elementwise on v2f
__device__ __forceinline__ v2f softplus2(v2f v) {
    v2f e = exp2v((v2f){-fabsf(v.x) * L2E, -fabsf(v.y) * L2E});
    return max2(v, splat2(0.f)) + (v2f){log1p_s(e.x), log1p_s(e.y)};
}

// ---- merged prep: rbf table + f16 decoder weight pack ----
// rbfc layout per pair kk (16 floats): cx(2), cy(2), q(2), w0(2), w1(2), pad(6)
// hb layout (units of h2): [0..49]=w1 row0, [50..99]=w1 row1, [100..149]=b1,
//   [150..199]=w2 col0, [200..249]=w2 col1; m-MLP at hb, f-MLP at hb+256.
__global__ __launch_bounds__(256) void prep(
    const float* __restrict__ Cc,   const float* __restrict__ Wc,
    const float* __restrict__ dmw1, const float* __restrict__ dmb1,
    const float* __restrict__ dmw2,
    const float* __restrict__ dfw1, const float* __restrict__ dfb1,
    const float* __restrict__ dfw2,
    float* __restrict__ rbfc, h2* __restrict__ hb)
{
    int t = threadIdx.x;
    if (t < KC / 2) {
        int k = 2 * t;
        float c00 = Cc[2 * k],     c01 = Cc[2 * k + 1];
        float c10 = Cc[2 * k + 2], c11 = Cc[2 * k + 3];
        float* p = &rbfc[16 * t];
        p[0] = 2.0f * LAM2E * c00;  p[1] = 2.0f * LAM2E * c10;
        p[2] = 2.0f * LAM2E * c01;  p[3] = 2.0f * LAM2E * c11;
        p[4] = -LAM2E * (c00 * c00 + c01 * c01);
        p[5] = -LAM2E * (c10 * c10 + c11 * c11);
        p[6] = fmaxf(Wc[2 * k],     0.f);  p[7] = fmaxf(Wc[2 * k + 2], 0.f);
        p[8] = fmaxf(Wc[2 * k + 1], 0.f);  p[9] = fmaxf(Wc[2 * k + 3], 0.f);
        p[10] = 0.f; p[11] = 0.f; p[12] = 0.f; p[13] = 0.f; p[14] = 0.f; p[15] = 0.f;
    }
    if (t >= 64 && t < 64 + HID / 2) {
        int tt = t - 64;
        int j = 2 * tt;
        h2* p = hb;
        p[tt]       = (h2){(_Float16)dmw1[j],        (_Float16)dmw1[j + 1]};
        p[50 + tt]  = (h2){(_Float16)dmw1[HID + j],  (_Float16)dmw1[HID + j + 1]};
        p[100 + tt] = (h2){(_Float16)dmb1[j],        (_Float16)dmb1[j + 1]};
        p[150 + tt] = (h2){(_Float16)dmw2[2 * j],    (_Float16)dmw2[2 * j + 2]};
        p[200 + tt] = (h2){(_Float16)dmw2[2 * j + 1],(_Float16)dmw2[2 * j + 3]};
    }
    if (t >= 128 && t < 128 + HID / 2) {
        int tt = t - 128;
        int j = 2 * tt;
        h2* p = hb + 256;
        p[tt]       = (h2){(_Float16)dfw1[j],        (_Float16)dfw1[j + 1]};
        p[50 + tt]  = (h2){(_Float16)dfw1[HID + j],  (_Float16)dfw1[HID + j + 1]};
        p[100 + tt] = (h2){(_Float16)dfb1[j],        (_Float16)dfb1[j + 1]};
        p[150 + tt] = (h2){(_Float16)dfw2[2 * j],    (_Float16)dfw2[2 * j + 2]};
        p[200 + tt] = (h2){(_Float16)dfw2[2 * j + 1],(_Float16)dfw2[2 * j + 3]};
    }
}

__global__ __launch_bounds__(256) void vae_main(
    const float* __restrict__ x,    const float* __restrict__ eps,
    const float* __restrict__ emw1, const float* __restrict__ emb1,
    const float* __restrict__ emw2, const float* __restrict__ emb2,
    const float* __restrict__ esw1, const float* __restrict__ esb1,
    const float* __restrict__ esw2, const float* __restrict__ esb2,
    const float* __restrict__ dmb2, const float* __restrict__ dfb2,
    const h2*    __restrict__ hb,
    const float* __restrict__ rbfc,
    float* __restrict__ out_xmu,   float* __restrict__ out_scale,
    float* __restrict__ out_z,     float* __restrict__ out_zmu,
    float* __restrict__ out_zstd,  float* __restrict__ partial,
    int n)
{
    const int i = blockIdx.x * 256 + threadIdx.x;

    float val = 0.0f;

    if (i < n) {
        const v2f xv = *(const v2f*)&x[2 * i];
        const v2f ev = *(const v2f*)&eps[2 * i];
        const v2f vx0 = splat2(xv.x), vx1 = splat2(xv.y);

        // ---- encoder MLPs (mu, std): f32 (z must be exact) ----
        v2f accm = splat2(0.f), accs = splat2(0.f);
#pragma unroll 10
        for (int j = 0; j < HID; j += 2) {
            v2f w1a = *(const v2f*)&emw1[j];
            v2f w1b = *(const v2f*)&emw1[HID + j];
            v2f b1  = *(const v2f*)&emb1[j];
            v2f h   = max2(fma2(vx0, w1a, fma2(vx1, w1b, b1)), splat2(0.f));
            v2f w2a = *(const v2f*)&emw2[2 * j];
            v2f w2b = *(const v2f*)&emw2[2 * j + 2];
            accm = fma2(splat2(h.x), w2a, accm);
            accm = fma2(splat2(h.y), w2b, accm);

            v2f s1a = *(const v2f*)&esw1[j];
            v2f s1b = *(const v2f*)&esw1[HID + j];
            v2f sb1 = *(const v2f*)&esb1[j];
            v2f hs  = max2(fma2(vx0, s1a, fma2(vx1, s1b, sb1)), splat2(0.f));
            v2f d0 = *(const v2f*)&esw2[2 * j];
            v2f d1 = *(const v2f*)&esw2[2 * j + 2];
            accs = fma2(splat2(hs.x), d0, accs);
            accs = fma2(splat2(hs.y), d1, accs);
        }
        const v2f zmu  = accm + *(const v2f*)&emb2[0];
        const v2f zstd = softplus2(accs + *(const v2f*)&esb2[0]);
        const v2f sig  = sqrt2(zstd);
        const v2f z    = fma2(sig, ev, zmu);

        // ---- decoder MLPs (mu, df): packed f16 layer1 + fdot2(f32-acc) layer2 ----
        const _Float16 z0f = (_Float16)z.x;
        const _Float16 z1f = (_Float16)z.y;
        const h2 z0h = (h2){z0f, z0f};
        const h2 z1h = (h2){z1f, z1f};
        const h2 hzero = {(_Float16)0.f, (_Float16)0.f};
        float dm0 = 0.f, dm1 = 0.f, dg0 = 0.f, dg1 = 0.f;
        const h2* hm = hb;
        const h2* hf = hb + 256;
#pragma unroll 10
        for (int jj = 0; jj < HID / 2; ++jj) {
            h2 pm = __builtin_elementwise_fma(z0h, hm[jj], hm[100 + jj]);
            pm = __builtin_elementwise_fma(z1h, hm[50 + jj], pm);
            pm = __builtin_elementwise_max(pm, hzero);
            dm0 = __builtin_amdgcn_fdot2(pm, hm[150 + jj], dm0, false);
            dm1 = __builtin_amdgcn_fdot2(pm, hm[200 + jj], dm1, false);

            h2 pf = __builtin_elementwise_fma(z0h, hf[jj], hf[100 + jj]);
            pf = __builtin_elementwise_fma(z1h, hf[50 + jj], pf);
            pf = __builtin_elementwise_max(pf, hzero);
            dg0 = __builtin_amdgcn_fdot2(pf, hf[150 + jj], dg0, false);
            dg1 = __builtin_amdgcn_fdot2(pf, hf[200 + jj], dg1, false);
        }
        const v2f xmu = (v2f){dm0, dm1} + *(const v2f*)&dmb2[0];
        const v2f df  = softplus2((v2f){dg0, dg1} + *(const v2f*)&dfb2[0]);

        // ---- RBF inverse-scale, pair-packed over k (f32, z exact) ----
        const float zz = z.x * z.x + z.y * z.y;
        const v2f z0s = splat2(z.x), z1s = splat2(z.y);
        const v2f u0s = splat2(-LAM2E * zz);
        v2f acc0 = splat2(0.f), acc1 = splat2(0.f);
#pragma unroll
        for (int kk = 0; kk < KC / 2; ++kk) {
            const float* p = &rbfc[16 * kk];
            v2f cx = *(const v2f*)&p[0];
            v2f cy = *(const v2f*)&p[2];
            v2f qq = *(const v2f*)&p[4];
            v2f w0p = *(const v2f*)&p[6];
            v2f w1p = *(const v2f*)&p[8];
            v2f arg = fma2(cx, z0s, fma2(cy, z1s, qq + u0s));
            v2f e = exp2v(arg);
            acc0 = fma2(e, w0p, acc0);
            acc1 = fma2(e, w1p, acc1);
        }
        const v2f ia = (v2f){acc0.x + acc0.y, acc1.x + acc1.y} + splat2(1e-10f);
        const v2f vscale = rcp2(ia);

        // ---- student-t log-prob sum over dims, log-product fused ----
        // lp_d = g(a) - 0.5 ln df - 0.5 ln pi + ln ia - 0.5(df+1) ln(1+u)
        // g(a) = lgamma(a+1/2)-lgamma(a) = 0.5 ln b + ln r + p(t), b=a+3, t=1/(2b)
        const v2f a  = splat2(0.5f) * df;
        const v2f b  = a + splat2(3.0f);
        const v2f rb = rcp2(b);
        const v2f t  = splat2(0.5f) * rb;
        const v2f t2 = t * t;
        const v2f p  = t * (splat2(-0.25f) + t2 * (splat2(0.0416666667f) + t2 * splat2(-0.05f)));

        const v2f a1 = a + splat2(1.0f), a2 = a + splat2(2.0f);
        const v2f h1 = a + splat2(0.5f), h2v = a + splat2(1.5f), h3 = a + splat2(2.5f);
        const v2f pn = a * a1 * a2;
        const v2f pd = h1 * h2v * h3;
        const float rprod = (pn.x * pn.y) * rcp_s(pd.x * pd.y);

        const v2f rdf = rcp2(df);
        const float bb_dd = (b.x * b.y) * (rdf.x * rdf.y);
        const float S1 = lg2_s(bb_dd);                       // log2(b.x b.y / (df.x df.y))
        const float S2 = lg2_s(rprod * (ia.x * ia.y));       // log2(r-prod * ia-prod)

        const v2f y  = (xv - xmu) * ia;
        const v2f u  = y * y * rdf;
        const v2f L2 = log2_1p2(u);
        const v2f dfp1 = df + splat2(1.0f);

        const float Szstd = lg2_s(zstd.x * zstd.y);          // for KL

        const float A = 0.5f * S1 + S2
                      - 0.5f * (dfp1.x * L2.x + dfp1.y * L2.y)
                      + 0.5f * Szstd;
        const float ee = ev.x * ev.x + ev.y * ev.y;
        val = LN2 * A + (p.x + p.y) - LOG_PI + 0.5f * ee - 0.5f * zz;

        // ---- outputs ----
        *(v2f*)&out_xmu[2 * i]   = xmu;
        *(v2f*)&out_scale[2 * i] = vscale;
        *(v2f*)&out_z[2 * i]     = z;
        *(v2f*)&out_zmu[2 * i]   = zmu;
        *(v2f*)&out_zstd[2 * i]  = zstd;
    }

    // ---- deterministic block reduction of val ----
#pragma unroll
    for (int off = 32; off > 0; off >>= 1)
        val += __shfl_down(val, off, 64);

    __shared__ float wsum[4];
    const int lane = threadIdx.x & 63;
    const int wid  = threadIdx.x >> 6;
    if (lane == 0) wsum[wid] = val;
    __syncthreads();
    if (threadIdx.x == 0)
        partial[blockIdx.x] = (wsum[0] + wsum[1]) + (wsum[2] + wsum[3]);
}

__global__ __launch_bounds__(256) void vae_reduce(
    const float* __restrict__ partial, int nblk, float* __restrict__ out, int n)
{
    __shared__ double sh[256];
    double acc = 0.0;
    for (int i = threadIdx.x; i < nblk; i += 256) acc += (double)partial[i];
    sh[threadIdx.x] = acc;
    __syncthreads();
#pragma unroll
    for (int s = 128; s > 0; s >>= 1) {
        if (threadIdx.x < s) sh[threadIdx.x] += sh[threadIdx.x + s];
        __syncthreads();
    }
    if (threadIdx.x == 0) out[0] = (float)(sh[0] / (double)n);
}

extern "C" void kernel_launch(void* const* d_in, const int* in_sizes, int n_in,
                              void* d_out, int out_size, void* d_ws, size_t ws_size,
                              hipStream_t stream) {
    const float* x    = (const float*)d_in[0];
    const float* eps  = (const float*)d_in[1];
    const float* emw1 = (const float*)d_in[2];
    const float* emb1 = (const float*)d_in[3];
    const float* emw2 = (const float*)d_in[4];
    const float* emb2 = (const float*)d_in[5];
    const float* esw1 = (const float*)d_in[6];
    const float* esb1 = (const float*)d_in[7];
    const float* esw2 = (const float*)d_in[8];
    const float* esb2 = (const float*)d_in[9];
    const float* dmw1 = (const float*)d_in[10];
    const float* dmb1 = (const float*)d_in[11];
    const float* dmw2 = (const float*)d_in[12];
    const float* dmb2 = (const float*)d_in[13];
    const float* dfw1 = (const float*)d_in[14];
    const float* dfb1 = (const float*)d_in[15];
    const float* dfw2 = (const float*)d_in[16];
    const float* dfb2 = (const float*)d_in[17];
    const float* Cc   = (const float*)d_in[18];
    const float* Wc   = (const float*)d_in[19];

    const int n = in_sizes[0] / 2;      // N samples
    float* out = (float*)d_out;
    float* out_elbo  = out;
    float* out_xmu   = out + 1;
    float* out_scale = out + 1 + 2 * (size_t)n;
    float* out_z     = out + 1 + 4 * (size_t)n;
    float* out_zmu   = out + 1 + 6 * (size_t)n;
    float* out_zstd  = out + 1 + 8 * (size_t)n;

    float* partial = (float*)d_ws;                    // [nblk] floats
    float* rbfc    = (float*)d_ws + 4096;             // [240] floats
    h2*    hb      = (h2*)((float*)d_ws + 8192);      // [512] half2

    const int nblk = (n + 255) / 256;

    prep<<<1, 256, 0, stream>>>(Cc, Wc, dmw1, dmb1, dmw2, dfw1, dfb1, dfw2,
                                rbfc, hb);

    vae_main<<<nblk, 256, 0, stream>>>(
        x, eps,
        emw1, emb1, emw2, emb2,
        esw1, esb1, esw2, esb2,
        dmb2, dfb2, hb, rbfc,
        out_xmu, out_scale, out_z, out_zmu, out_zstd,
        partial, n);

    vae_reduce<<<1, 256, 0, stream>>>(partial, nblk, out_elbo, n);
}